// Round 11
// baseline (434.955 us; speedup 1.0000x reference)
//
#include <hip/hip_runtime.h>
#include <cmath>

typedef unsigned short u16;
typedef unsigned int   u32;
typedef __attribute__((ext_vector_type(8))) __bf16 bf16x8;
typedef __attribute__((ext_vector_type(4))) float  f32x4;
typedef __attribute__((ext_vector_type(8))) unsigned short u16x8;
typedef __attribute__((ext_vector_type(4))) unsigned short u16x4;

#define DEV __device__ __forceinline__

DEV float bf2f(u16 u){ union{u32 i; float f;} v; v.i=((u32)u)<<16; return v.f; }
DEV u16 f2bf(float f){ union{float f; u32 i;} v; v.f=f; u32 r=v.i+0x7fffu+((v.i>>16)&1u); return (u16)(r>>16); }

#if defined(__has_builtin) && __has_builtin(__builtin_amdgcn_global_load_lds)
DEV void gld16(const void* g, void* l){
  __builtin_amdgcn_global_load_lds((__attribute__((address_space(1))) void*)g,
                                   (__attribute__((address_space(3))) void*)l, 16, 0, 0);
}
#else
DEV void gld16(const void* g, void* l){ *(u16x8*)l = *(const u16x8*)g; }
#endif

#if defined(__has_builtin) && __has_builtin(__builtin_amdgcn_exp2f)
DEV float fexp2(float x){ return __builtin_amdgcn_exp2f(x); }
#else
DEV float fexp2(float x){ return exp2f(x); }
#endif

// Inline dtype probe (flag semantics: 1 -> fp32 inputs). Reads first 64 u16
// of x (same cache line for all threads; L1-broadcast, negligible).
DEV bool probe_f32(const u16* __restrict__ x)
{
  int sane = 0;
#pragma unroll
  for (int i = 0; i < 64; ++i){
    int e = (x[i] >> 7) & 0xFF;
    sane += (e >= 100 && e <= 150);
  }
  return sane < 56;
}

// Canonicalize the 8 small vectors (gammas/betas/biases) to fp32.
// Also publishes *flagw for later dispatches (block 0) — detect_k fused away.
// dst layout: [ln1_g 0 | ln1_b 512 | bqkv 1024 | bm 6144 | ln2_g 6656 |
//              ln2_b 7168 | b1 7680 | b2 9728]  total 10240.
__global__ __launch_bounds__(256)
void conv_vecs(const void* a0,const void* a1,const void* a2,const void* a3,
               const void* a4,const void* a5,const void* a6,const void* a7,
               float* __restrict__ dst, const u16* __restrict__ xp,
               int* __restrict__ flagw)
{
  const bool f32 = probe_f32(xp);
  if (blockIdx.x==0 && threadIdx.x==0) *flagw = f32 ? 1 : 0;
  int i = blockIdx.x*256 + threadIdx.x;
  if (i >= 10240) return;
  const void* src; int off;
  if      (i < 512)  { src=a0; off=i; }
  else if (i < 1024) { src=a1; off=i-512; }
  else if (i < 6144) { src=a2; off=i-1024; }
  else if (i < 6656) { src=a3; off=i-6144; }
  else if (i < 7168) { src=a4; off=i-6656; }
  else if (i < 7680) { src=a5; off=i-7168; }
  else if (i < 9728) { src=a6; off=i-7680; }
  else               { src=a7; off=i-9728; }
  dst[i] = f32 ? ((const float*)src)[off] : bf2f(((const u16*)src)[off]);
}

// XOR-swizzled chunk index for staging: lane writes LDS chunk c (fixed by HW);
// it must LOAD global chunk (row=c>>3, kc=(c&7)^(row&7)).
#define SWZ_SRC(c) (((c)&7) ^ (((c)>>3)&7))

// Reuse-aware XCD block remap (grids are %8-divisible -> bijective).
// SWZ 0: none. SWZ 1: x-chunked per XCD (B-slice L2-resident), x-fast within.
// SWZ 2: y-chunked per XCD (A-slice L2-resident), y-fast within.
template<int SWZ>
DEV void remap_xcd(int& bx, int& by)
{
  if (SWZ==1){
    int L = by*(int)gridDim.x + bx;
    int xcd = L & 7, l = L >> 3;
    int chunk = (int)gridDim.x >> 3;
    bx = xcd*chunk + (l % chunk);
    by = l / chunk;
  } else if (SWZ==2){
    int L = by*(int)gridDim.x + bx;
    int xcd = L & 7, l = L >> 3;
    int chunk = (int)gridDim.y >> 3;
    by = xcd*chunk + (l % chunk);
    bx = l / chunk;
  }
}

// ---------------------------------------------------------------------------
// 128x128-tile bf16 GEMM, A row-major (M x K), BT row-major (N x K).
// 512 threads / 8 waves (2x4 wave grid, per-wave 64x32 out, acc[4][2]);
// double-buffered 2-phase staging. LDS 64 KB -> 2 blocks/CU.
// MODE 0: out bf16 = acc + bias
// MODE 2: out bf16 = swish(acc + bias)
// VT: v-range tiles (n0>=1024) written TRANSPOSED to vout (per-head V^T)
//     via one-pass 128x132-padded LDS bounce in the dead staging buffers.
// ---------------------------------------------------------------------------
template<int MODE, int SWZ, bool VT>
__global__ __launch_bounds__(512)
void gemm_bt(const u16* __restrict__ A, const u16* __restrict__ BT,
             void* __restrict__ C, const float* __restrict__ bias,
             int K, int lda, int ldb, int ldc, u16* __restrict__ vout)
{
  __shared__ u16 AB[4*128*64];      // As dbuf | Bs dbuf (VT epilogue reuses)
  u16* As0 = AB;                    // As[bi] = As0 + bi*8192
  u16* Bs0 = AB + 2*128*64;         // Bs[bi] = Bs0 + bi*8192
  const int tid  = threadIdx.x;
  const int lane = tid & 63;
  const int quad = lane>>4, l7 = lane&7, l15 = lane&15;
  const int wv   = tid >> 6;
  const int wm   = wv >> 2, wn = wv & 3;   // 2x4 wave grid
  int bx = blockIdx.x, by = blockIdx.y;
  remap_xcd<SWZ>(bx, by);
  const long m0 = (long)by * 128;
  const long n0 = (long)bx * 128;

  f32x4 acc[4][2];
#pragma unroll
  for (int i=0;i<4;i++)
#pragma unroll
    for (int j=0;j<2;j++) acc[i][j] = (f32x4){0.f,0.f,0.f,0.f};

  auto stage = [&](int bi, int k0){
#pragma unroll
    for (int i=0;i<2;i++){
      int c = i*512 + tid;
      gld16(A  + (m0 + (c>>3))*lda + k0 + SWZ_SRC(c)*8, &As0[bi*8192 + c*8]);
      gld16(BT + (n0 + (c>>3))*ldb + k0 + SWZ_SRC(c)*8, &Bs0[bi*8192 + c*8]);
    }
  };

  const int S = K >> 6;
  stage(0, 0);
  __syncthreads();   // drain prologue stage

  for (int s=0; s<S; ++s){
    const int cb = s & 1;
    if (s+1 < S) stage(cb^1, (s+1)<<6);
#pragma unroll
    for (int kk=0;kk<2;kk++){
      const int ch = ((kk*4 + quad) ^ l7) * 8;
      bf16x8 af[4], bfr[2];
#pragma unroll
      for (int t=0;t<4;t++)
        af[t]  = *(const bf16x8*)&As0[cb*8192 + (wm*64 + t*16 + l15)*64 + ch];
#pragma unroll
      for (int t=0;t<2;t++)
        bfr[t] = *(const bf16x8*)&Bs0[cb*8192 + (wn*32 + t*16 + l15)*64 + ch];
#pragma unroll
      for (int ti=0;ti<4;ti++)
#pragma unroll
        for (int tj=0;tj<2;tj++)
          acc[ti][tj] = __builtin_amdgcn_mfma_f32_16x16x32_bf16(af[ti], bfr[tj], acc[ti][tj], 0,0,0);
    }
    __syncthreads();   // drains next-stage loads (covered by this compute)
  }

  if (VT && n0 >= 1024){
    // --- one-pass transposed epilogue: (tokens m0..+127) x (cols n0..+127) ---
    const int hh   = (int)((n0 - 1024) >> 9);
    const int c0   = (int)((n0 - 1024) & 511);
    const int b_   = (int)(m0 >> 11);
    const int kloc = (int)(m0 & 2047);
    u16* vb = vout + ((long)(b_*8 + hh))*512*2048 + kloc;
    u16* Ts = AB;                       // 128*132 u16 = 33 KB, fits in AB
#pragma unroll
    for (int ti=0;ti<4;ti++)
#pragma unroll
    for (int tj=0;tj<2;tj++)
#pragma unroll
    for (int r=0;r<4;r++){
      int row = wm*64 + ti*16 + quad*4 + r;    // token-local
      int cl  = wn*32 + tj*16 + l15;           // v-col within tile
      Ts[row*132 + cl] = f2bf(acc[ti][tj][r] + bias[n0 + cl]);
    }
    __syncthreads();
    // coalesced transposed store: 128 c-rows x 128 contiguous tokens
#pragma unroll
    for (int step=0; step<4; ++step){
      int cr = step*32 + (tid>>4);
      int t8 = (tid&15)*8;
      u16x8 pk;
#pragma unroll
      for (int j=0;j<8;j++) pk[j] = Ts[(t8+j)*132 + cr];
      *(u16x8*)(vb + (long)(c0 + cr)*2048 + t8) = pk;
    }
    return;
  }

#pragma unroll
  for (int ti=0;ti<4;ti++)
#pragma unroll
  for (int tj=0;tj<2;tj++)
#pragma unroll
  for (int r=0;r<4;r++){
    long row = m0 + wm*64 + ti*16 + quad*4 + r;
    long col = n0 + wn*32 + tj*16 + l15;
    float v = acc[ti][tj][r] + bias[col];
    if (MODE==2) v = v / (1.f + __expf(-v));
    ((u16*)C)[row*ldc+col] = f2bf(v);
  }
}

// ---------------------------------------------------------------------------
// 128x64-tile bf16 GEMM for narrow-N outputs (N=512). Swizzled LDS.
// 512 threads / 8 waves (2 waves/SIMD at 1 block/CU). Each wave owns 16 rows.
// Double-buffered 2-phase staging (measured-best R8 form).
// MODE 1: out f32 = acc + bias + residual (dtype per flag)   (x2)
// MODE 3: out (dtype per flag) = acc + bias + f32 residual   (final)
// ---------------------------------------------------------------------------
template<int MODE, int SWZ>
__global__ __launch_bounds__(512)
void gemm_n64(const u16* __restrict__ A, const u16* __restrict__ BT,
              void* __restrict__ C, const float* __restrict__ bias,
              const void* __restrict__ res,
              int K, int lda, int ldb, int ldc, const int* __restrict__ flag)
{
  __shared__ u16 As[2][128*64];   // 32 KB
  __shared__ u16 Bs[2][64*64];    // 16 KB
  const int tid  = threadIdx.x;
  const int lane = tid & 63;
  const int quad = lane>>4, l7 = lane&7, l15 = lane&15;
  const int wm   = tid >> 6;          // 8 waves, 16 rows each
  int bx = blockIdx.x, by = blockIdx.y;
  remap_xcd<SWZ>(bx, by);
  const long m0 = (long)by * 128;
  const long n0 = (long)bx * 64;
  const bool f32io = flag && (*flag != 0);

  f32x4 acc[4];
#pragma unroll
  for (int j=0;j<4;j++) acc[j] = (f32x4){0.f,0.f,0.f,0.f};

  auto stage = [&](int bi, int k0){
#pragma unroll
    for (int i=0;i<2;i++){
      int c = i*512 + tid;
      gld16(A + (m0 + (c>>3))*lda + k0 + SWZ_SRC(c)*8, &As[bi][c*8]);
    }
    { int c = tid;
      gld16(BT + (n0 + (c>>3))*ldb + k0 + SWZ_SRC(c)*8, &Bs[bi][c*8]); }
  };

  const int S = K >> 6;
  stage(0, 0);
  __syncthreads();   // drain prologue stage

  for (int s=0; s<S; ++s){
    const int cb = s & 1;
    if (s+1 < S) stage(cb^1, (s+1)<<6);
#pragma unroll
    for (int kk=0;kk<2;kk++){
      const int ch = ((kk*4 + quad) ^ l7) * 8;
      bf16x8 af = *(const bf16x8*)&As[cb][(wm*16 + l15)*64 + ch];
      bf16x8 bfr[4];
#pragma unroll
      for (int t=0;t<4;t++)
        bfr[t] = *(const bf16x8*)&Bs[cb][(t*16 + l15)*64 + ch];
#pragma unroll
      for (int tj=0;tj<4;tj++)
        acc[tj] = __builtin_amdgcn_mfma_f32_16x16x32_bf16(af, bfr[tj], acc[tj], 0,0,0);
    }
    __syncthreads();   // drains next-stage loads (covered by this compute)
  }

#pragma unroll
  for (int tj=0;tj<4;tj++)
#pragma unroll
  for (int r=0;r<4;r++){
    long row = m0 + wm*16 + quad*4 + r;
    long col = n0 + tj*16 + l15;
    float v = acc[tj][r] + bias[col];
    if (MODE==1){
      v += f32io ? ((const float*)res)[row*ldc+col]
                 : bf2f(((const u16*)res)[row*ldc+col]);
      ((float*)C)[row*ldc+col] = v;
    } else {
      v += ((const float*)res)[row*ldc+col];
      if (f32io) ((float*)C)[row*ldc+col] = v;
      else       ((u16*)C)[row*ldc+col]   = f2bf(v);
    }
  }
}

// ---------------------------------------------------------------------------
// Flash attention v3: occupancy 2 blocks/CU (the one untried lever).
// q-tile 64, kv-tile 32, grid 512 (32 qt x 16 bh), 512 threads.
// LDS ~46 KB: Vs 32K single (4-chunk-row XOR swizzle) + Ks dbuf 8K + Ps 4.5K;
// Q direct to regs (no Qs). __launch_bounds__(512,4) -> VGPR<=128 ->
// 2 blocks/CU = 4 waves/SIMD (vs 2 before: the latency-exposure fix).
// Schedule = R8's exactly: stage V[mt]+K[mt+1] -> S -> stats -> barrier ->
// PV -> barrier. S/stats on waves 0-3 only (16 FULL rows each, so R8's
// per-wave-tile max normalization is unchanged); PV on all 8 waves
// (each: all 64 rows x 64 cols, o[4][4]); l via ones-MFMA on wave 0.
// ---------------------------------------------------------------------------
__global__ __launch_bounds__(512, 4)
void att_flash(const u16* __restrict__ qkv, const u16* __restrict__ vt,
               u16* __restrict__ ao)
{
  __shared__ u16 Ks[2][32*64];    //  8 KB (dbuf, 8-chunk-row XOR swizzle)
  __shared__ u16 Ps[64*36];       //  4.5 KB (padded rows, stride 36)
  __shared__ u16 Vs[512*32];      // 32 KB (4-chunk-row XOR swizzle)
  __shared__ float alph[4];       // per-S-wave alpha (16 rows each)
  __shared__ float l_lds[64];
  __shared__ int resc[2];
  const int tid=threadIdx.x, lane=tid&63, wv=tid>>6;
  const int quad=lane>>4, l7=lane&7, l15=lane&15;
  // XCD-chunked swizzle of the 512 linear blocks (512%8==0 -> bijective);
  // qt fast within id -> 64 consecutive ids/XCD = 2 heads (V L2-resident).
  const int bid = blockIdx.x;
  const int id  = ((bid&7)<<6) + (bid>>3);
  const int qt  = id & 31, bh = id >> 5;
  const int b = bh>>3, h = bh&7;
  const long q0 = (long)qt*64;
  const u16* qb = qkv + ((long)b*2048 + q0)*5120 + h*64;
  const u16* kb = qkv + (long)b*2048*5120 + 512 + h*64;
  const u16* vb = vt + (long)bh*512*2048;

  // Q -> regs (S-waves only: wave wv<4 owns rows wv*16..+15)
  bf16x8 qreg[2];
  if (wv < 4){
#pragma unroll
    for (int kk=0;kk<2;kk++)
      qreg[kk] = *(const bf16x8*)(qb + (long)(wv*16 + l15)*5120 + (kk*4+quad)*8);
  }
  // K[0]: 32 rows x 64 cols = 256 chunks
  if (tid < 256){ int c=tid; gld16(kb + (long)(c>>3)*5120 + SWZ_SRC(c)*8, &Ks[0][c*8]); }
  if (tid==0){ resc[0]=0; resc[1]=0; }

  // ones B-fragment (bf16 1.0 = 0x3F80) for the l-column MFMA
  union { u16x8 u; bf16x8 v; } one_u;
#pragma unroll
  for (int j=0;j<8;j++) one_u.u[j] = 0x3F80;
  const bf16x8 ones = one_u.v;

  f32x4 o[4][4];                  // all 64 rows x (this wave's 64 cols)
#pragma unroll
  for (int i=0;i<4;i++)
#pragma unroll
    for (int j=0;j<4;j++) o[i][j] = (f32x4){0.f,0.f,0.f,0.f};
  f32x4 ol[4];                    // l accumulator (meaningful in wave 0)
#pragma unroll
  for (int i=0;i<4;i++) ol[i] = (f32x4){0.f,0.f,0.f,0.f};
  float m_w = -1e30f;             // per-S-wave running max (16 rows)

  __syncthreads();   // K[0] staged; resc init visible

  for (int mt=0; mt<64; ++mt){
    const int cur = mt&1;
    const long m0 = (long)mt*32;

    // stage V[mt] (512 rows x 32 cols; row = 4 chunks, XOR row&3) and K[mt+1]
#pragma unroll
    for (int i=0;i<4;i++){
      int c = i*512 + tid;              // 0..2047
      int row = c>>2, k4 = c&3;
      gld16(vb + (long)row*2048 + m0 + ((k4 ^ (row&3)))*8, &Vs[c*8]);
    }
    if (mt < 63 && tid < 256){
      int c = tid;
      gld16(kb + (m0+32 + (c>>3))*5120 + SWZ_SRC(c)*8, &Ks[cur^1][c*8]);
    }
    if (tid==0) resc[cur^1] = 0;

    // --- S + stats: waves 0-3 (16 full rows x 32 kv each) ---
    if (wv < 4){
      f32x4 s[2];
      s[0] = (f32x4){0.f,0.f,0.f,0.f}; s[1] = (f32x4){0.f,0.f,0.f,0.f};
#pragma unroll
      for (int kk=0;kk<2;kk++){
        const int ch = ((kk*4 + quad) ^ l7) * 8;
#pragma unroll
        for (int tj=0;tj<2;tj++){
          bf16x8 bfr = *(const bf16x8*)&Ks[cur][(tj*16 + l15)*64 + ch];
          s[tj] = __builtin_amdgcn_mfma_f32_16x16x32_bf16(qreg[kk], bfr, s[tj], 0,0,0);
        }
      }
      // wave-tile max (defer-max THR=8), exp2-folded P
      float vm = fmaxf(fmaxf(fmaxf(s[0][0],s[0][1]),fmaxf(s[0][2],s[0][3])),
                       fmaxf(fmaxf(s[1][0],s[1][1]),fmaxf(s[1][2],s[1][3])));
      vm = fmaxf(vm, __shfl_xor(vm,1));  vm = fmaxf(vm, __shfl_xor(vm,2));
      vm = fmaxf(vm, __shfl_xor(vm,4));  vm = fmaxf(vm, __shfl_xor(vm,8));
      vm = fmaxf(vm, __shfl_xor(vm,16)); vm = fmaxf(vm, __shfl_xor(vm,32));
      const float vs = vm*0.125f;
      const bool c_ = (vs > m_w + 8.f);        // wave-uniform
      const float nm = c_ ? vs : m_w;
      const float al = c_ ? __expf(m_w - nm) : 1.f;
      m_w = nm;
      const float nml = nm*1.44269504f;
#pragma unroll
      for (int tj=0;tj<2;tj++)
#pragma unroll
      for (int r=0;r<4;r++){
        float pv = fexp2(fmaf(s[tj][r], 0.18033688f, -nml));
        Ps[(wv*16 + quad*4 + r)*36 + tj*16 + l15] = f2bf(pv);
      }
      if (lane==0){ alph[wv] = al; if (c_) resc[cur] = 1; }
    }
    __syncthreads();   // Ps/alph/resc ready; V[mt]+K[mt+1] drained (vmcnt 0)

    // --- PV: all 8 waves; P(64x32) x V^T(32x512); wave owns cols wv*64..+63
    if (resc[cur]){
      float a_[4];
#pragma unroll
      for (int ti=0;ti<4;ti++) a_[ti] = alph[ti];
#pragma unroll
      for (int ti=0;ti<4;ti++)
#pragma unroll
      for (int tj=0;tj<4;tj++)
#pragma unroll
        for (int r=0;r<4;r++) o[ti][tj][r] *= a_[ti];
      if (wv==0){
#pragma unroll
        for (int ti=0;ti<4;ti++)
#pragma unroll
          for (int r=0;r<4;r++) ol[ti][r] *= a_[ti];
      }
    }
    {
      bf16x8 af[4], bfr[4];
#pragma unroll
      for (int t=0;t<4;t++){
        int base = (t*16 + l15)*36 + quad*8;
        union { u16x4 hh[2]; bf16x8 v; } u;
        u.hh[0] = *(const u16x4*)&Ps[base];
        u.hh[1] = *(const u16x4*)&Ps[base+4];
        af[t] = u.v;
      }
#pragma unroll
      for (int t=0;t<4;t++){
        int cr = wv*64 + t*16 + l15;
        int p  = (quad ^ (cr&3)) * 8;
        bfr[t] = *(const bf16x8*)&Vs[cr*32 + p];
      }
#pragma unroll
      for (int ti=0;ti<4;ti++)
#pragma unroll
        for (int tj=0;tj<4;tj++)
          o[ti][tj] = __builtin_amdgcn_mfma_f32_16x16x32_bf16(af[ti], bfr[tj], o[ti][tj], 0,0,0);
      if (wv==0){
#pragma unroll
        for (int ti=0;ti<4;ti++)
          ol[ti] = __builtin_amdgcn_mfma_f32_16x16x32_bf16(af[ti], ones, ol[ti], 0,0,0);
      }
    }
    __syncthreads();   // PV reads done -> Vs/Ps/Ks[cur] may be overwritten
  }

  // epilogue: share l (wave 0 owns it), then O /= l
  if (wv==0 && l15==0){
#pragma unroll
    for (int ti=0;ti<4;ti++)
#pragma unroll
      for (int r=0;r<4;r++) l_lds[ti*16 + quad*4 + r] = ol[ti][r];
  }
  __syncthreads();
  float rl[4][4];
#pragma unroll
  for (int ti=0;ti<4;ti++)
#pragma unroll
    for (int r=0;r<4;r++) rl[ti][r] = 1.f / l_lds[ti*16 + quad*4 + r];
#pragma unroll
  for (int ti=0;ti<4;ti++)
#pragma unroll
  for (int tj=0;tj<4;tj++)
#pragma unroll
  for (int r=0;r<4;r++){
    long rown = q0 + ti*16 + quad*4 + r;
    long col  = wv*64 + tj*16 + l15;
    ao[((long)b*2048 + rown)*4096 + (long)h*512 + col] = f2bf(o[ti][tj][r]*rl[ti][r]);
  }
}

// ---------------------------------------------------------------------------
// LayerNorm: one wave per row of 512. SRC=0: input dtype per flag (x),
// SRC=1: fp32 input (x2).
// ---------------------------------------------------------------------------
template<int SRC>
__global__ __launch_bounds__(256)
void ln_kernel(const void* __restrict__ xin, const float* __restrict__ g,
               const float* __restrict__ bb, u16* __restrict__ out,
               const int* __restrict__ flag)
{
  const int tid=threadIdx.x, lane=tid&63, wv=tid>>6;
  const long row = (long)blockIdx.x*4 + wv;
  const bool f32 = (SRC==1) || (flag && *flag != 0);
  float v[8];
  if (f32){
    const float* xr = (const float*)xin + row*512 + lane*8;
#pragma unroll
    for (int j=0;j<8;j++) v[j]=xr[j];
  } else {
    const u16* xr = (const u16*)xin + row*512 + lane*8;
    u16x8 xv = *(const u16x8*)xr;
#pragma unroll
    for (int j=0;j<8;j++) v[j]=bf2f(xv[j]);
  }
  float s1=0.f, s2=0.f;
#pragma unroll
  for (int j=0;j<8;j++){ s1+=v[j]; s2+=v[j]*v[j]; }
  for (int off=1; off<64; off<<=1){ s1+=__shfl_xor(s1,off); s2+=__shfl_xor(s2,off); }
  float mu  = s1*(1.f/512.f);
  float var = s2*(1.f/512.f) - mu*mu;
  float rs  = rsqrtf(var + 1e-5f);
  u16x8 ov;
#pragma unroll
  for (int j=0;j<8;j++){
    int col = lane*8+j;
    ov[j] = f2bf((v[j]-mu)*rs*g[col] + bb[col]);
  }
  *(u16x8*)(out + row*512 + lane*8) = ov;
}

// ---------------------------------------------------------------------------
// Fused weight transposes: all 4 weight matrices in ONE dispatch.
// Unified 1D grid over 32x32 tiles; scalar decode of (matrix, tile).
//   m0: Wqkv [512][5120] -> wqkvT [5120][512]   tiles 160x16 = 2560
//   m1: Wm   [4096][512] -> wmT   [512][4096]   tiles  16x128= 2048
//   m2: W1   [512][2048] -> w1T   [2048][512]   tiles  64x16 = 1024
//   m3: W2   [2048][512] -> w2T   [512][2048]   tiles  16x64 = 1024
// total 6656 tiles. Input dtype per flag.
// ---------------------------------------------------------------------------
__global__ __launch_bounds__(256)
void transpose_all(const void* __restrict__ i0, const void* __restrict__ i1,
                   const void* __restrict__ i2, const void* __restrict__ i3,
                   u16* __restrict__ o0, u16* __restrict__ o1,
                   u16* __restrict__ o2, u16* __restrict__ o3,
                   const int* __restrict__ flag)
{
  __shared__ u16 t[32][33];
  const int bt = blockIdx.x;
  const void* in_; u16* out; int ldi, ldo, txn, lt;
  if (bt < 2560)      { in_=i0; out=o0; ldi=5120; ldo=512;  txn=160; lt=bt; }
  else if (bt < 4608) { in_=i1; out=o1; ldi=512;  ldo=4096; txn=16;  lt=bt-2560; }
  else if (bt < 5632) { in_=i2; out=o2; ldi=2048; ldo=512;  txn=64;  lt=bt-4608; }
  else                { in_=i3; out=o3; ldi=512;  ldo=2048; txn=16;  lt=bt-5632; }
  const int bx = lt % txn, by = lt / txn;
  const bool f32 = *flag != 0;
  const int tx = threadIdx.x, ty = threadIdx.y;
  const long c  = (long)bx*32 + tx;
  const long r0 = (long)by*32;
  if (f32){
    const float* in = (const float*)in_;
#pragma unroll
    for (int j=0;j<4;j++) t[ty+j*8][tx] = f2bf(in[(r0+ty+j*8)*ldi + c]);
  } else {
    const u16* in = (const u16*)in_;
#pragma unroll
    for (int j=0;j<4;j++) t[ty+j*8][tx] = in[(r0+ty+j*8)*ldi + c];
  }
  __syncthreads();
  const long rr = r0 + tx;
  const long cc = (long)bx*32 + ty;
#pragma unroll
  for (int j=0;j<4;j++) out[(cc+j*8)*ldo + rr] = t[tx][ty+j*8];
}

// ---------------------------------------------------------------------------
extern "C" void kernel_launch(void* const* d_in, const int* in_sizes, int n_in,
                              void* d_out, int out_size, void* d_ws, size_t ws_size,
                              hipStream_t stream)
{
  const void* x    = d_in[0];
  const void* ln1g = d_in[1];
  const void* ln1b = d_in[2];
  const void* Wqkv = d_in[3];
  const void* bqkv = d_in[4];
  const void* Wm   = d_in[5];
  const void* bm   = d_in[6];
  const void* ln2g = d_in[7];
  const void* ln2b = d_in[8];
  const void* W1   = d_in[9];
  const void* b1   = d_in[10];
  const void* W2   = d_in[11];
  const void* b2   = d_in[12];

  char* p = (char*)d_ws;
  auto take = [&](size_t n){ void* r=(void*)p; p += (n + 255) & ~(size_t)255; return r; };
  u16*   lnb   = (u16*)  take((size_t)4096*512*2);       // ln1 out, later ln2 out
  u16*   qkv   = (u16*)  take((size_t)4096*5120*2);      // q|k rows (v unused); later hb
  u16*   vtb   = (u16*)  take((size_t)16*512*2048*2);    // per-head V^T; later x2
  u16*   wqkvT = (u16*)  take((size_t)5120*512*2);
  u16*   wmT   = (u16*)  take((size_t)512*4096*2);
  u16*   w1T   = (u16*)  take((size_t)2048*512*2);
  u16*   w2T   = (u16*)  take((size_t)512*2048*2);
  u16*   ao    = (u16*)  take((size_t)4096*4096*2);      // attention out (B*N, H*512)
  float* cvec  = (float*)take((size_t)10240*4);          // canonical fp32 small vectors
  int*   flag  = (int*)  take(4);
  float* x2    = (float*)vtb;                            // overlay: vtb dead after att_flash
  u16*   hb    = qkv;                                    // overlay: qkv dead after attention

  // small vectors + dtype probe (detect_k fused into conv_vecs)
  conv_vecs<<<40, 256, 0, stream>>>(ln1g, ln1b, bqkv, bm, ln2g, ln2b, b1, b2,
                                    cvec, (const u16*)x, flag);

  // all 4 weight transposes in one dispatch
  transpose_all<<<6656, dim3(32,8), 0, stream>>>(Wqkv, Wm, W1, W2,
                                                 wqkvT, wmT, w1T, w2T, flag);

  // ln1 -> qkv (q,k normal; v tiles written transposed directly to vtb)
  ln_kernel<0><<<1024, 256, 0, stream>>>(x, cvec+0, cvec+512, lnb, flag);
  gemm_bt<0,1,true><<<dim3(40,32), 512, 0, stream>>>(lnb, wqkvT, qkv, cvec+1024,
                                                     512, 512, 512, 5120, vtb);

  // fused flash attention v3 (q=64, kv=32, 2 blocks/CU)
  att_flash<<<dim3(512), 512, 0, stream>>>(qkv, vtb, ao);

  // x2 = x + ao@Wm + bm  (y-chunked swizzle: A-slice 4MB/XCD L2-resident)
  gemm_n64<1,2><<<dim3(8,32), 512, 0, stream>>>(ao, wmT, x2, cvec+6144, x,
                                                4096, 4096, 4096, 512, flag);
  // ln2, MLP
  ln_kernel<1><<<1024, 256, 0, stream>>>(x2, cvec+6656, cvec+7168, lnb, nullptr);
  gemm_bt<2,2,false><<<dim3(16,32), 512, 0, stream>>>(lnb, w1T, hb, cvec+7680,
                                                      512, 512, 512, 2048, nullptr);
  gemm_n64<3,2><<<dim3(8,32), 512, 0, stream>>>(hb, w2T, d_out, cvec+9728, x2,
                                                2048, 2048, 2048, 512, flag);
}

// Round 12
// 353.533 us; speedup vs baseline: 1.2303x; 1.2303x over previous
//
#include <hip/hip_runtime.h>
#include <cmath>

typedef unsigned short u16;
typedef unsigned int   u32;
typedef __attribute__((ext_vector_type(8))) __bf16 bf16x8;
typedef __attribute__((ext_vector_type(4))) float  f32x4;
typedef __attribute__((ext_vector_type(8))) unsigned short u16x8;
typedef __attribute__((ext_vector_type(4))) unsigned short u16x4;

#define DEV __device__ __forceinline__

DEV float bf2f(u16 u){ union{u32 i; float f;} v; v.i=((u32)u)<<16; return v.f; }
DEV u16 f2bf(float f){ union{float f; u32 i;} v; v.f=f; u32 r=v.i+0x7fffu+((v.i>>16)&1u); return (u16)(r>>16); }

#if defined(__has_builtin) && __has_builtin(__builtin_amdgcn_global_load_lds)
DEV void gld16(const void* g, void* l){
  __builtin_amdgcn_global_load_lds((__attribute__((address_space(1))) void*)g,
                                   (__attribute__((address_space(3))) void*)l, 16, 0, 0);
}
#else
DEV void gld16(const void* g, void* l){ *(u16x8*)l = *(const u16x8*)g; }
#endif

#if defined(__has_builtin) && __has_builtin(__builtin_amdgcn_exp2f)
DEV float fexp2(float x){ return __builtin_amdgcn_exp2f(x); }
#else
DEV float fexp2(float x){ return exp2f(x); }
#endif

// Inline dtype probe (flag semantics: 1 -> fp32 inputs). Reads first 64 u16
// of x (same cache line for all threads; L1-broadcast, negligible).
DEV bool probe_f32(const u16* __restrict__ x)
{
  int sane = 0;
#pragma unroll
  for (int i = 0; i < 64; ++i){
    int e = (x[i] >> 7) & 0xFF;
    sane += (e >= 100 && e <= 150);
  }
  return sane < 56;
}

// Canonicalize the 8 small vectors (gammas/betas/biases) to fp32.
// Also publishes *flagw for later dispatches (block 0) — detect_k fused away.
// dst layout: [ln1_g 0 | ln1_b 512 | bqkv 1024 | bm 6144 | ln2_g 6656 |
//              ln2_b 7168 | b1 7680 | b2 9728]  total 10240.
__global__ __launch_bounds__(256)
void conv_vecs(const void* a0,const void* a1,const void* a2,const void* a3,
               const void* a4,const void* a5,const void* a6,const void* a7,
               float* __restrict__ dst, const u16* __restrict__ xp,
               int* __restrict__ flagw)
{
  const bool f32 = probe_f32(xp);
  if (blockIdx.x==0 && threadIdx.x==0) *flagw = f32 ? 1 : 0;
  int i = blockIdx.x*256 + threadIdx.x;
  if (i >= 10240) return;
  const void* src; int off;
  if      (i < 512)  { src=a0; off=i; }
  else if (i < 1024) { src=a1; off=i-512; }
  else if (i < 6144) { src=a2; off=i-1024; }
  else if (i < 6656) { src=a3; off=i-6144; }
  else if (i < 7168) { src=a4; off=i-6656; }
  else if (i < 7680) { src=a5; off=i-7168; }
  else if (i < 9728) { src=a6; off=i-7680; }
  else               { src=a7; off=i-9728; }
  dst[i] = f32 ? ((const float*)src)[off] : bf2f(((const u16*)src)[off]);
}

// XOR-swizzled chunk index for staging: lane writes LDS chunk c (fixed by HW);
// it must LOAD global chunk (row=c>>3, kc=(c&7)^(row&7)).
#define SWZ_SRC(c) (((c)&7) ^ (((c)>>3)&7))

// Reuse-aware XCD block remap (grids are %8-divisible -> bijective).
// SWZ 0: none. SWZ 1: x-chunked per XCD (B-slice L2-resident), x-fast within.
// SWZ 2: y-chunked per XCD (A-slice L2-resident), y-fast within.
template<int SWZ>
DEV void remap_xcd(int& bx, int& by)
{
  if (SWZ==1){
    int L = by*(int)gridDim.x + bx;
    int xcd = L & 7, l = L >> 3;
    int chunk = (int)gridDim.x >> 3;
    bx = xcd*chunk + (l % chunk);
    by = l / chunk;
  } else if (SWZ==2){
    int L = by*(int)gridDim.x + bx;
    int xcd = L & 7, l = L >> 3;
    int chunk = (int)gridDim.y >> 3;
    by = xcd*chunk + (l % chunk);
    bx = l / chunk;
  }
}

// ---------------------------------------------------------------------------
// 128x128-tile bf16 GEMM, A row-major (M x K), BT row-major (N x K).
// 512 threads / 8 waves (2x4 wave grid, per-wave 64x32 out, acc[4][2]);
// double-buffered 2-phase staging. LDS 64 KB -> 2 blocks/CU.
// MODE 0: out bf16 = acc + bias
// MODE 2: out bf16 = swish(acc + bias)
// VT: v-range tiles (n0>=1024) written TRANSPOSED to vout (per-head V^T)
//     via one-pass 128x132-padded LDS bounce in the dead staging buffers.
// ---------------------------------------------------------------------------
template<int MODE, int SWZ, bool VT>
__global__ __launch_bounds__(512)
void gemm_bt(const u16* __restrict__ A, const u16* __restrict__ BT,
             void* __restrict__ C, const float* __restrict__ bias,
             int K, int lda, int ldb, int ldc, u16* __restrict__ vout)
{
  __shared__ u16 AB[4*128*64];      // As dbuf | Bs dbuf (VT epilogue reuses)
  u16* As0 = AB;                    // As[bi] = As0 + bi*8192
  u16* Bs0 = AB + 2*128*64;         // Bs[bi] = Bs0 + bi*8192
  const int tid  = threadIdx.x;
  const int lane = tid & 63;
  const int quad = lane>>4, l7 = lane&7, l15 = lane&15;
  const int wv   = tid >> 6;
  const int wm   = wv >> 2, wn = wv & 3;   // 2x4 wave grid
  int bx = blockIdx.x, by = blockIdx.y;
  remap_xcd<SWZ>(bx, by);
  const long m0 = (long)by * 128;
  const long n0 = (long)bx * 128;

  f32x4 acc[4][2];
#pragma unroll
  for (int i=0;i<4;i++)
#pragma unroll
    for (int j=0;j<2;j++) acc[i][j] = (f32x4){0.f,0.f,0.f,0.f};

  auto stage = [&](int bi, int k0){
#pragma unroll
    for (int i=0;i<2;i++){
      int c = i*512 + tid;
      gld16(A  + (m0 + (c>>3))*lda + k0 + SWZ_SRC(c)*8, &As0[bi*8192 + c*8]);
      gld16(BT + (n0 + (c>>3))*ldb + k0 + SWZ_SRC(c)*8, &Bs0[bi*8192 + c*8]);
    }
  };

  const int S = K >> 6;
  stage(0, 0);
  __syncthreads();   // drain prologue stage

  for (int s=0; s<S; ++s){
    const int cb = s & 1;
    if (s+1 < S) stage(cb^1, (s+1)<<6);
#pragma unroll
    for (int kk=0;kk<2;kk++){
      const int ch = ((kk*4 + quad) ^ l7) * 8;
      bf16x8 af[4], bfr[2];
#pragma unroll
      for (int t=0;t<4;t++)
        af[t]  = *(const bf16x8*)&As0[cb*8192 + (wm*64 + t*16 + l15)*64 + ch];
#pragma unroll
      for (int t=0;t<2;t++)
        bfr[t] = *(const bf16x8*)&Bs0[cb*8192 + (wn*32 + t*16 + l15)*64 + ch];
#pragma unroll
      for (int ti=0;ti<4;ti++)
#pragma unroll
        for (int tj=0;tj<2;tj++)
          acc[ti][tj] = __builtin_amdgcn_mfma_f32_16x16x32_bf16(af[ti], bfr[tj], acc[ti][tj], 0,0,0);
    }
    __syncthreads();   // drains next-stage loads (covered by this compute)
  }

  if (VT && n0 >= 1024){
    // --- one-pass transposed epilogue: (tokens m0..+127) x (cols n0..+127) ---
    const int hh   = (int)((n0 - 1024) >> 9);
    const int c0   = (int)((n0 - 1024) & 511);
    const int b_   = (int)(m0 >> 11);
    const int kloc = (int)(m0 & 2047);
    u16* vb = vout + ((long)(b_*8 + hh))*512*2048 + kloc;
    u16* Ts = AB;                       // 128*132 u16 = 33 KB, fits in AB
#pragma unroll
    for (int ti=0;ti<4;ti++)
#pragma unroll
    for (int tj=0;tj<2;tj++)
#pragma unroll
    for (int r=0;r<4;r++){
      int row = wm*64 + ti*16 + quad*4 + r;    // token-local
      int cl  = wn*32 + tj*16 + l15;           // v-col within tile
      Ts[row*132 + cl] = f2bf(acc[ti][tj][r] + bias[n0 + cl]);
    }
    __syncthreads();
    // coalesced transposed store: 128 c-rows x 128 contiguous tokens
#pragma unroll
    for (int step=0; step<4; ++step){
      int cr = step*32 + (tid>>4);
      int t8 = (tid&15)*8;
      u16x8 pk;
#pragma unroll
      for (int j=0;j<8;j++) pk[j] = Ts[(t8+j)*132 + cr];
      *(u16x8*)(vb + (long)(c0 + cr)*2048 + t8) = pk;
    }
    return;
  }

#pragma unroll
  for (int ti=0;ti<4;ti++)
#pragma unroll
  for (int tj=0;tj<2;tj++)
#pragma unroll
  for (int r=0;r<4;r++){
    long row = m0 + wm*64 + ti*16 + quad*4 + r;
    long col = n0 + wn*32 + tj*16 + l15;
    float v = acc[ti][tj][r] + bias[col];
    if (MODE==2) v = v / (1.f + __expf(-v));
    ((u16*)C)[row*ldc+col] = f2bf(v);
  }
}

// ---------------------------------------------------------------------------
// 128x64-tile bf16 GEMM for narrow-N outputs (N=512). Swizzled LDS.
// 512 threads / 8 waves (2 waves/SIMD at 1 block/CU). Each wave owns 16 rows.
// Double-buffered 2-phase staging (measured-best R8 form).
// MODE 1: out f32 = acc + bias + residual (dtype per flag)   (x2)
// MODE 3: out (dtype per flag) = acc + bias + f32 residual   (final)
// ---------------------------------------------------------------------------
template<int MODE, int SWZ>
__global__ __launch_bounds__(512)
void gemm_n64(const u16* __restrict__ A, const u16* __restrict__ BT,
              void* __restrict__ C, const float* __restrict__ bias,
              const void* __restrict__ res,
              int K, int lda, int ldb, int ldc, const int* __restrict__ flag)
{
  __shared__ u16 As[2][128*64];   // 32 KB
  __shared__ u16 Bs[2][64*64];    // 16 KB
  const int tid  = threadIdx.x;
  const int lane = tid & 63;
  const int quad = lane>>4, l7 = lane&7, l15 = lane&15;
  const int wm   = tid >> 6;          // 8 waves, 16 rows each
  int bx = blockIdx.x, by = blockIdx.y;
  remap_xcd<SWZ>(bx, by);
  const long m0 = (long)by * 128;
  const long n0 = (long)bx * 64;
  const bool f32io = flag && (*flag != 0);

  f32x4 acc[4];
#pragma unroll
  for (int j=0;j<4;j++) acc[j] = (f32x4){0.f,0.f,0.f,0.f};

  auto stage = [&](int bi, int k0){
#pragma unroll
    for (int i=0;i<2;i++){
      int c = i*512 + tid;
      gld16(A + (m0 + (c>>3))*lda + k0 + SWZ_SRC(c)*8, &As[bi][c*8]);
    }
    { int c = tid;
      gld16(BT + (n0 + (c>>3))*ldb + k0 + SWZ_SRC(c)*8, &Bs[bi][c*8]); }
  };

  const int S = K >> 6;
  stage(0, 0);
  __syncthreads();   // drain prologue stage

  for (int s=0; s<S; ++s){
    const int cb = s & 1;
    if (s+1 < S) stage(cb^1, (s+1)<<6);
#pragma unroll
    for (int kk=0;kk<2;kk++){
      const int ch = ((kk*4 + quad) ^ l7) * 8;
      bf16x8 af = *(const bf16x8*)&As[cb][(wm*16 + l15)*64 + ch];
      bf16x8 bfr[4];
#pragma unroll
      for (int t=0;t<4;t++)
        bfr[t] = *(const bf16x8*)&Bs[cb][(t*16 + l15)*64 + ch];
#pragma unroll
      for (int tj=0;tj<4;tj++)
        acc[tj] = __builtin_amdgcn_mfma_f32_16x16x32_bf16(af, bfr[tj], acc[tj], 0,0,0);
    }
    __syncthreads();   // drains next-stage loads (covered by this compute)
  }

#pragma unroll
  for (int tj=0;tj<4;tj++)
#pragma unroll
  for (int r=0;r<4;r++){
    long row = m0 + wm*16 + quad*4 + r;
    long col = n0 + tj*16 + l15;
    float v = acc[tj][r] + bias[col];
    if (MODE==1){
      v += f32io ? ((const float*)res)[row*ldc+col]
                 : bf2f(((const u16*)res)[row*ldc+col]);
      ((float*)C)[row*ldc+col] = v;
    } else {
      v += ((const float*)res)[row*ldc+col];
      if (f32io) ((float*)C)[row*ldc+col] = v;
      else       ((u16*)C)[row*ldc+col]   = f2bf(v);
    }
  }
}

// ---------------------------------------------------------------------------
// Single-pass flash attention, full c-width (512): O = softmax(QK^T/8) @ V.
// One block per (q-tile 128, head): grid 256 = 1 block/CU, 512 threads.
// Round-4 SCHEDULE (kv-tile 64, K dbuf, V staged under S+stats).
// Round-8 WORK reduction (measured 116-118 us): per-wave-tile max (6 shfl),
// l via ones-column MFMA in PV (0 sum-shfls).
// R11's occupancy variant (q=64,kv=32, 2 blocks/CU) regressed to 216 us
// (bank conflicts + doubled per-tile overhead) — this structure is final.
// ---------------------------------------------------------------------------
__global__ __launch_bounds__(512, 2)
void att_flash(const u16* __restrict__ qkv, const u16* __restrict__ vt,
               u16* __restrict__ ao)
{
  __shared__ u16 Qs[128*64];      // 16 KB (swizzled; read once into regs)
  __shared__ u16 Ks[2][64*64];    // 16 KB (dbuf, swizzled)
  __shared__ u16 Ps[128*68];      // 17 KB (padded rows)
  __shared__ u16 Vs[512*64];      // 64 KB (swizzled)
  __shared__ float alph[8];       // per-S-wave alpha (group of 16 rows)
  __shared__ float l_lds[128];
  __shared__ int resc[2];
  const int tid=threadIdx.x, lane=tid&63, wv=tid>>6;
  const int wm=wv>>2, wn=wv&3;          // PV wave grid 2x4 (64 rows x 128 cols)
  const int quad=lane>>4, l7=lane&7, l15=lane&15;
  // XCD-chunked swizzle of the 256 linear blocks (256%8==0 -> bijective)
  const int bid = blockIdx.x;
  const int id  = ((bid&7)<<5) + (bid>>3);
  const int qt  = id & 15, bh = id >> 4;
  const int b = bh>>3, h = bh&7;
  const long q0 = (long)qt*128;
  const u16* qb = qkv + ((long)b*2048 + q0)*5120 + h*64;
  const u16* kb = qkv + (long)b*2048*5120 + 512 + h*64;
  const u16* vb = vt + (long)bh*512*2048;

#pragma unroll
  for (int i=0;i<2;i++){
    int c=i*512+tid;
    gld16(qb + (long)(c>>3)*5120 + SWZ_SRC(c)*8, &Qs[c*8]);
  }
  { int c=tid; gld16(kb + (long)(c>>3)*5120 + SWZ_SRC(c)*8, &Ks[0][c*8]); }
  if (tid==0){ resc[0]=0; resc[1]=0; }

  // ones B-fragment (bf16 1.0 = 0x3F80) for the l-column MFMA
  union { u16x8 u; bf16x8 v; } one_u;
#pragma unroll
  for (int j=0;j<8;j++) one_u.u[j] = 0x3F80;
  const bf16x8 ones = one_u.v;

  f32x4 o[4][8];
#pragma unroll
  for (int i=0;i<4;i++)
#pragma unroll
    for (int j=0;j<8;j++) o[i][j] = (f32x4){0.f,0.f,0.f,0.f};
  f32x4 ol[4];                      // l accumulator (meaningful in wn==0 waves)
#pragma unroll
  for (int i=0;i<4;i++) ol[i] = (f32x4){0.f,0.f,0.f,0.f};
  float m_w = -1e30f;               // per-wave running max (wave owns 16 S-rows)

  __syncthreads();   // Qs ready (drains prologue staging)
  bf16x8 qreg[2];
#pragma unroll
  for (int kk=0;kk<2;kk++)
    qreg[kk] = *(const bf16x8*)&Qs[(wv*16 + l15)*64 + ((kk*4 + quad) ^ l7)*8];

  for (int mt=0; mt<32; ++mt){
    const long m0 = (long)mt*64;
    const int cur = mt&1;
    __syncthreads();   // prev PV done (Vs/Ps/resc[cur^1] free); prev staging drained

    // prefetch K[mt+1] into the other K buffer; stage V[mt] (drains at pre-PV bar)
    if (mt < 31){ int c=tid; gld16(kb + (m0+64 + (c>>3))*5120 + SWZ_SRC(c)*8, &Ks[cur^1][c*8]); }
#pragma unroll
    for (int i=0;i<8;i++){
      int c=i*512+tid;
      gld16(vb + (long)(c>>3)*2048 + m0 + SWZ_SRC(c)*8, &Vs[c*8]);
    }
    if (tid==0) resc[cur^1] = 0;

    // --- S: rows wv*16..+15, cols 0..63 (Q from regs) ---
    f32x4 s[4];
#pragma unroll
    for (int j=0;j<4;j++) s[j] = (f32x4){0.f,0.f,0.f,0.f};
#pragma unroll
    for (int kk=0;kk<2;kk++){
      const int ch = ((kk*4 + quad) ^ l7) * 8;
#pragma unroll
      for (int tj=0;tj<4;tj++){
        bf16x8 bfr = *(const bf16x8*)&Ks[cur][(tj*16 + l15)*64 + ch];
        s[tj] = __builtin_amdgcn_mfma_f32_16x16x32_bf16(qreg[kk], bfr, s[tj], 0,0,0);
      }
    }

    // --- stats: wave-tile max (defer-max THR=8), exp2-folded P ---
    float vm = s[0][0];
#pragma unroll
    for (int tj=0;tj<4;tj++)
#pragma unroll
      for (int r=0;r<4;r++) vm = fmaxf(vm, s[tj][r]);
    vm = fmaxf(vm, __shfl_xor(vm,1));  vm = fmaxf(vm, __shfl_xor(vm,2));
    vm = fmaxf(vm, __shfl_xor(vm,4));  vm = fmaxf(vm, __shfl_xor(vm,8));
    vm = fmaxf(vm, __shfl_xor(vm,16)); vm = fmaxf(vm, __shfl_xor(vm,32));
    const float vs = vm*0.125f;
    const bool c_ = (vs > m_w + 8.f);        // wave-uniform
    const float nm = c_ ? vs : m_w;
    const float al = c_ ? __expf(m_w - nm) : 1.f;
    m_w = nm;
    const float nml = nm*1.44269504f;
#pragma unroll
    for (int tj=0;tj<4;tj++)
#pragma unroll
    for (int r=0;r<4;r++){
      // p = exp(s/8 - m) = exp2(s*0.125*log2e - m*log2e); bounded by e^8
      float pv = fexp2(fmaf(s[tj][r], 0.18033688f, -nml));
      Ps[(wv*16 + quad*4 + r)*68 + tj*16 + l15] = f2bf(pv);
    }
    if (lane==0){ alph[wv] = al; if (c_) resc[cur] = 1; }
    __syncthreads();   // Ps/alph/resc ready; V[mt] + K[mt+1] drained (vmcnt(0))

    // --- PV: (rare) rescale O,l by alpha; accumulate P x V^T and l = P @ 1 ---
    if (resc[cur]){
      float a_[4];
#pragma unroll
      for (int ti=0;ti<4;ti++) a_[ti] = alph[wm*4 + ti];
#pragma unroll
      for (int ti=0;ti<4;ti++)
#pragma unroll
      for (int tj=0;tj<8;tj++)
#pragma unroll
        for (int r=0;r<4;r++) o[ti][tj][r] *= a_[ti];
      if (wn==0){
#pragma unroll
        for (int ti=0;ti<4;ti++)
#pragma unroll
          for (int r=0;r<4;r++) ol[ti][r] *= a_[ti];
      }
    }
#pragma unroll
    for (int kk=0;kk<2;kk++){
      const int ch = ((kk*4 + quad) ^ l7) * 8;
      bf16x8 af[4], bfr[8];
#pragma unroll
      for (int t=0;t<4;t++){
        int base = (wm*64 + t*16 + l15)*68 + kk*32 + quad*8;
        union { u16x4 hh[2]; bf16x8 v; } u;
        u.hh[0] = *(const u16x4*)&Ps[base];
        u.hh[1] = *(const u16x4*)&Ps[base+4];
        af[t] = u.v;
      }
#pragma unroll
      for (int t=0;t<8;t++)
        bfr[t] = *(const bf16x8*)&Vs[(wn*128 + t*16 + l15)*64 + ch];
#pragma unroll
      for (int ti=0;ti<4;ti++)
#pragma unroll
        for (int tj=0;tj<8;tj++)
          o[ti][tj] = __builtin_amdgcn_mfma_f32_16x16x32_bf16(af[ti], bfr[tj], o[ti][tj], 0,0,0);
      if (wn==0){
#pragma unroll
        for (int ti=0;ti<4;ti++)
          ol[ti] = __builtin_amdgcn_mfma_f32_16x16x32_bf16(af[ti], ones, ol[ti], 0,0,0);
      }
    }
  }

  // epilogue: share l (wn==0 waves own it), then O /= l
  if (wn==0 && l15==0){
#pragma unroll
    for (int ti=0;ti<4;ti++)
#pragma unroll
      for (int r=0;r<4;r++) l_lds[wm*64 + ti*16 + quad*4 + r] = ol[ti][r];
  }
  __syncthreads();
  float rl[4][4];
#pragma unroll
  for (int ti=0;ti<4;ti++)
#pragma unroll
    for (int r=0;r<4;r++) rl[ti][r] = 1.f / l_lds[wm*64 + ti*16 + quad*4 + r];
#pragma unroll
  for (int ti=0;ti<4;ti++)
#pragma unroll
  for (int tj=0;tj<8;tj++)
#pragma unroll
  for (int r=0;r<4;r++){
    long rown = q0 + wm*64 + ti*16 + quad*4 + r;
    long col  = wn*128 + tj*16 + l15;
    ao[((long)b*2048 + rown)*4096 + (long)h*512 + col] = f2bf(o[ti][tj][r]*rl[ti][r]);
  }
}

// ---------------------------------------------------------------------------
// LayerNorm: one wave per row of 512. SRC=0: input dtype per flag (x),
// SRC=1: fp32 input (x2).
// ---------------------------------------------------------------------------
template<int SRC>
__global__ __launch_bounds__(256)
void ln_kernel(const void* __restrict__ xin, const float* __restrict__ g,
               const float* __restrict__ bb, u16* __restrict__ out,
               const int* __restrict__ flag)
{
  const int tid=threadIdx.x, lane=tid&63, wv=tid>>6;
  const long row = (long)blockIdx.x*4 + wv;
  const bool f32 = (SRC==1) || (flag && *flag != 0);
  float v[8];
  if (f32){
    const float* xr = (const float*)xin + row*512 + lane*8;
#pragma unroll
    for (int j=0;j<8;j++) v[j]=xr[j];
  } else {
    const u16* xr = (const u16*)xin + row*512 + lane*8;
    u16x8 xv = *(const u16x8*)xr;
#pragma unroll
    for (int j=0;j<8;j++) v[j]=bf2f(xv[j]);
  }
  float s1=0.f, s2=0.f;
#pragma unroll
  for (int j=0;j<8;j++){ s1+=v[j]; s2+=v[j]*v[j]; }
  for (int off=1; off<64; off<<=1){ s1+=__shfl_xor(s1,off); s2+=__shfl_xor(s2,off); }
  float mu  = s1*(1.f/512.f);
  float var = s2*(1.f/512.f) - mu*mu;
  float rs  = rsqrtf(var + 1e-5f);
  u16x8 ov;
#pragma unroll
  for (int j=0;j<8;j++){
    int col = lane*8+j;
    ov[j] = f2bf((v[j]-mu)*rs*g[col] + bb[col]);
  }
  *(u16x8*)(out + row*512 + lane*8) = ov;
}

// ---------------------------------------------------------------------------
// Fused weight transposes: all 4 weight matrices in ONE dispatch.
// Unified 1D grid over 32x32 tiles; scalar decode of (matrix, tile).
//   m0: Wqkv [512][5120] -> wqkvT [5120][512]   tiles 160x16 = 2560
//   m1: Wm   [4096][512] -> wmT   [512][4096]   tiles  16x128= 2048
//   m2: W1   [512][2048] -> w1T   [2048][512]   tiles  64x16 = 1024
//   m3: W2   [2048][512] -> w2T   [512][2048]   tiles  16x64 = 1024
// total 6656 tiles. Input dtype per flag.
// ---------------------------------------------------------------------------
__global__ __launch_bounds__(256)
void transpose_all(const void* __restrict__ i0, const void* __restrict__ i1,
                   const void* __restrict__ i2, const void* __restrict__ i3,
                   u16* __restrict__ o0, u16* __restrict__ o1,
                   u16* __restrict__ o2, u16* __restrict__ o3,
                   const int* __restrict__ flag)
{
  __shared__ u16 t[32][33];
  const int bt = blockIdx.x;
  const void* in_; u16* out; int ldi, ldo, txn, lt;
  if (bt < 2560)      { in_=i0; out=o0; ldi=5120; ldo=512;  txn=160; lt=bt; }
  else if (bt < 4608) { in_=i1; out=o1; ldi=512;  ldo=4096; txn=16;  lt=bt-2560; }
  else if (bt < 5632) { in_=i2; out=o2; ldi=2048; ldo=512;  txn=64;  lt=bt-4608; }
  else                { in_=i3; out=o3; ldi=512;  ldo=2048; txn=16;  lt=bt-5632; }
  const int bx = lt % txn, by = lt / txn;
  const bool f32 = *flag != 0;
  const int tx = threadIdx.x, ty = threadIdx.y;
  const long c  = (long)bx*32 + tx;
  const long r0 = (long)by*32;
  if (f32){
    const float* in = (const float*)in_;
#pragma unroll
    for (int j=0;j<4;j++) t[ty+j*8][tx] = f2bf(in[(r0+ty+j*8)*ldi + c]);
  } else {
    const u16* in = (const u16*)in_;
#pragma unroll
    for (int j=0;j<4;j++) t[ty+j*8][tx] = in[(r0+ty+j*8)*ldi + c];
  }
  __syncthreads();
  const long rr = r0 + tx;
  const long cc = (long)bx*32 + ty;
#pragma unroll
  for (int j=0;j<4;j++) out[(cc+j*8)*ldo + rr] = t[tx][ty+j*8];
}

// ---------------------------------------------------------------------------
extern "C" void kernel_launch(void* const* d_in, const int* in_sizes, int n_in,
                              void* d_out, int out_size, void* d_ws, size_t ws_size,
                              hipStream_t stream)
{
  const void* x    = d_in[0];
  const void* ln1g = d_in[1];
  const void* ln1b = d_in[2];
  const void* Wqkv = d_in[3];
  const void* bqkv = d_in[4];
  const void* Wm   = d_in[5];
  const void* bm   = d_in[6];
  const void* ln2g = d_in[7];
  const void* ln2b = d_in[8];
  const void* W1   = d_in[9];
  const void* b1   = d_in[10];
  const void* W2   = d_in[11];
  const void* b2   = d_in[12];

  char* p = (char*)d_ws;
  auto take = [&](size_t n){ void* r=(void*)p; p += (n + 255) & ~(size_t)255; return r; };
  u16*   lnb   = (u16*)  take((size_t)4096*512*2);       // ln1 out, later ln2 out
  u16*   qkv   = (u16*)  take((size_t)4096*5120*2);      // q|k rows (v unused); later hb
  u16*   vtb   = (u16*)  take((size_t)16*512*2048*2);    // per-head V^T; later x2
  u16*   wqkvT = (u16*)  take((size_t)5120*512*2);
  u16*   wmT   = (u16*)  take((size_t)512*4096*2);
  u16*   w1T   = (u16*)  take((size_t)2048*512*2);
  u16*   w2T   = (u16*)  take((size_t)512*2048*2);
  u16*   ao    = (u16*)  take((size_t)4096*4096*2);      // attention out (B*N, H*512)
  float* cvec  = (float*)take((size_t)10240*4);          // canonical fp32 small vectors
  int*   flag  = (int*)  take(4);
  float* x2    = (float*)vtb;                            // overlay: vtb dead after att_flash
  u16*   hb    = qkv;                                    // overlay: qkv dead after attention

  // small vectors + dtype probe (detect_k fused into conv_vecs)
  conv_vecs<<<40, 256, 0, stream>>>(ln1g, ln1b, bqkv, bm, ln2g, ln2b, b1, b2,
                                    cvec, (const u16*)x, flag);

  // all 4 weight transposes in one dispatch
  transpose_all<<<6656, dim3(32,8), 0, stream>>>(Wqkv, Wm, W1, W2,
                                                 wqkvT, wmT, w1T, w2T, flag);

  // ln1 -> qkv (q,k normal; v tiles written transposed directly to vtb)
  ln_kernel<0><<<1024, 256, 0, stream>>>(x, cvec+0, cvec+512, lnb, flag);
  gemm_bt<0,1,true><<<dim3(40,32), 512, 0, stream>>>(lnb, wqkvT, qkv, cvec+1024,
                                                     512, 512, 512, 5120, vtb);

  // fused flash attention (round-4 schedule + round-8 work reduction; final)
  att_flash<<<dim3(256), 512, 0, stream>>>(qkv, vtb, ao);

  // x2 = x + ao@Wm + bm  (y-chunked swizzle: A-slice 4MB/XCD L2-resident)
  gemm_n64<1,2><<<dim3(8,32), 512, 0, stream>>>(ao, wmT, x2, cvec+6144, x,
                                                4096, 4096, 4096, 512, flag);
  // ln2, MLP
  ln_kernel<1><<<1024, 256, 0, stream>>>(x2, cvec+6656, cvec+7168, lnb, nullptr);
  gemm_bt<2,2,false><<<dim3(16,32), 512, 0, stream>>>(lnb, w1T, hb, cvec+7680,
                                                      512, 512, 512, 2048, nullptr);
  gemm_n64<3,2><<<dim3(8,32), 512, 0, stream>>>(hb, w2T, d_out, cvec+9728, x2,
                                                2048, 2048, 2048, 512, flag);
}